// Round 1
// baseline (805.731 us; speedup 1.0000x reference)
//
#include <hip/hip_runtime.h>

typedef unsigned int  uint32;
typedef float  f32x4  __attribute__((ext_vector_type(4)));
typedef __bf16 bf16x8 __attribute__((ext_vector_type(8)));

__device__ __forceinline__ float bf2f(unsigned int u) {
  return __builtin_bit_cast(float, u << 16);
}
__device__ __forceinline__ unsigned short f2bf(float f) {
  uint32 u = __builtin_bit_cast(uint32, f);
  u += 0x7fffu + ((u >> 16) & 1u);          // RNE
  return (unsigned short)(u >> 16);
}

__device__ __forceinline__ void gload_lds16(const void* g, void* l) {
  __builtin_amdgcn_global_load_lds(
      (const __attribute__((address_space(1))) void*)g,
      (__attribute__((address_space(3))) void*)l, 16, 0, 0);
}

// ---------------- fp32 -> bf16 cast (8 elems/thread) ----------------
__global__ __launch_bounds__(256) void cast_kernel(
    const float* __restrict__ x, unsigned short* __restrict__ y, int n8) {
  int i = blockIdx.x * 256 + threadIdx.x;
  if (i >= n8) return;
  const float4* xp = (const float4*)x;
  float4 a = xp[2 * i], b = xp[2 * i + 1];
  uint4 o;
  o.x = (uint32)f2bf(a.x) | ((uint32)f2bf(a.y) << 16);
  o.y = (uint32)f2bf(a.z) | ((uint32)f2bf(a.w) << 16);
  o.z = (uint32)f2bf(b.x) | ((uint32)f2bf(b.y) << 16);
  o.w = (uint32)f2bf(b.z) | ((uint32)f2bf(b.w) << 16);
  ((uint4*)y)[i] = o;
}

// ---------------- bf16 GEMM: C[M,N] = A[M,K] * W[N,K]^T + bias ----------------
// EPI=0: bf16 out.  EPI=1: fp32 out = acc + bias + resid.
// 128x128 tile, BK=32, 4 waves (2x2), 4x4 16x16x32 MFMA frags per wave.
template <int EPI>
__global__ __launch_bounds__(256) void gemm_bt(
    const unsigned short* __restrict__ A, const unsigned short* __restrict__ W,
    const float* __restrict__ bias, const float* __restrict__ resid,
    unsigned short* __restrict__ Ob, float* __restrict__ Of,
    int M, int N, int K) {
  __shared__ unsigned short At[128 * 32];
  __shared__ unsigned short Bt[128 * 32];
  const int tid  = threadIdx.x;
  const int lane = tid & 63;
  const int wave = tid >> 6;
  const int wr = wave >> 1, wc = wave & 1;
  const int m0 = blockIdx.x * 128;   // m-fastest for W-panel L2 reuse
  const int n0 = blockIdx.y * 128;

  f32x4 acc[4][4];
#pragma unroll
  for (int m = 0; m < 4; ++m)
#pragma unroll
    for (int n = 0; n < 4; ++n) acc[m][n] = (f32x4)0.0f;

  const int srow = tid >> 2;            // 0..63 staging row
  const int scol = (tid & 3) * 8;       // 0/8/16/24 elem col
  const unsigned short* Ag0 = A + (size_t)(m0 + srow) * K + scol;
  const unsigned short* Ag1 = A + (size_t)(m0 + 64 + srow) * K + scol;
  const unsigned short* Wg0 = W + (size_t)(n0 + srow) * K + scol;
  const unsigned short* Wg1 = W + (size_t)(n0 + 64 + srow) * K + scol;
  unsigned short* lA0 = &At[wave * 512];
  unsigned short* lA1 = &At[2048 + wave * 512];
  unsigned short* lB0 = &Bt[wave * 512];
  unsigned short* lB1 = &Bt[2048 + wave * 512];

  const int fr = lane & 15, fk = (lane >> 4) * 8;

  for (int k0 = 0; k0 < K; k0 += 32) {
    gload_lds16(Ag0 + k0, lA0);
    gload_lds16(Ag1 + k0, lA1);
    gload_lds16(Wg0 + k0, lB0);
    gload_lds16(Wg1 + k0, lB1);
    __syncthreads();
    bf16x8 af[4], bfv[4];
#pragma unroll
    for (int m = 0; m < 4; ++m)
      af[m] = *(const bf16x8*)&At[(wr * 64 + m * 16 + fr) * 32 + fk];
#pragma unroll
    for (int n = 0; n < 4; ++n)
      bfv[n] = *(const bf16x8*)&Bt[(wc * 64 + n * 16 + fr) * 32 + fk];
#pragma unroll
    for (int m = 0; m < 4; ++m)
#pragma unroll
      for (int n = 0; n < 4; ++n)
        acc[m][n] = __builtin_amdgcn_mfma_f32_16x16x32_bf16(af[m], bfv[n],
                                                            acc[m][n], 0, 0, 0);
    __syncthreads();
  }

  const int r4 = (lane >> 4) * 4;
#pragma unroll
  for (int n = 0; n < 4; ++n) {
    const int col = n0 + wc * 64 + n * 16 + fr;
    const float bv = bias[col];
#pragma unroll
    for (int m = 0; m < 4; ++m) {
      const int row = m0 + wr * 64 + m * 16 + r4;
#pragma unroll
      for (int i = 0; i < 4; ++i) {
        const size_t idx = (size_t)(row + i) * N + col;
        float v = acc[m][n][i] + bv;
        if constexpr (EPI == 0) {
          Ob[idx] = f2bf(v);
        } else {
          Of[idx] = v + resid[idx];
        }
      }
    }
  }
}

// ---------------- head-wise attention, one wave per row b ----------------
// Q,K,V: [B, 16 heads, 64 dims] bf16.  Out: [B, 1024] with idx = d*16 + h.
__global__ __launch_bounds__(256) void attn_kernel(
    const unsigned short* __restrict__ Q, const unsigned short* __restrict__ K,
    const unsigned short* __restrict__ V, unsigned short* __restrict__ O) {
  __shared__ float pl[4][16][16];
  const int tid  = threadIdx.x;
  const int lane = tid & 63;
  const int wave = tid >> 6;
  const int b = blockIdx.x * 4 + wave;
  const int h = lane >> 2, p = lane & 3;
  const size_t base = (size_t)b * 1024;

  // ---- phase 1: scores + softmax; lane (h,p) owns Q/K[h, p*16 .. p*16+15]
  float qf[16], kf[16];
  {
    const uint4* qp = (const uint4*)(Q + base + h * 64 + p * 16);
    const uint4* kp = (const uint4*)(K + base + h * 64 + p * 16);
    uint4 v0 = qp[0], v1 = qp[1];
    qf[0] = bf2f(v0.x & 0xffff); qf[1] = bf2f(v0.x >> 16);
    qf[2] = bf2f(v0.y & 0xffff); qf[3] = bf2f(v0.y >> 16);
    qf[4] = bf2f(v0.z & 0xffff); qf[5] = bf2f(v0.z >> 16);
    qf[6] = bf2f(v0.w & 0xffff); qf[7] = bf2f(v0.w >> 16);
    qf[8]  = bf2f(v1.x & 0xffff); qf[9]  = bf2f(v1.x >> 16);
    qf[10] = bf2f(v1.y & 0xffff); qf[11] = bf2f(v1.y >> 16);
    qf[12] = bf2f(v1.z & 0xffff); qf[13] = bf2f(v1.z >> 16);
    qf[14] = bf2f(v1.w & 0xffff); qf[15] = bf2f(v1.w >> 16);
    uint4 k0 = kp[0], k1 = kp[1];
    kf[0] = bf2f(k0.x & 0xffff); kf[1] = bf2f(k0.x >> 16);
    kf[2] = bf2f(k0.y & 0xffff); kf[3] = bf2f(k0.y >> 16);
    kf[4] = bf2f(k0.z & 0xffff); kf[5] = bf2f(k0.z >> 16);
    kf[6] = bf2f(k0.w & 0xffff); kf[7] = bf2f(k0.w >> 16);
    kf[8]  = bf2f(k1.x & 0xffff); kf[9]  = bf2f(k1.x >> 16);
    kf[10] = bf2f(k1.y & 0xffff); kf[11] = bf2f(k1.y >> 16);
    kf[12] = bf2f(k1.z & 0xffff); kf[13] = bf2f(k1.z >> 16);
    kf[14] = bf2f(k1.w & 0xffff); kf[15] = bf2f(k1.w >> 16);
  }

  float sc[16];
#pragma unroll
  for (int g = 0; g < 16; ++g) {
    const int src = g * 4 + p;
    float s = 0.f;
#pragma unroll
    for (int j = 0; j < 16; ++j) s += qf[j] * __shfl(kf[j], src, 64);
    sc[g] = s;
  }
#pragma unroll
  for (int g = 0; g < 16; ++g) {
    sc[g] += __shfl_xor(sc[g], 1, 64);
    sc[g] += __shfl_xor(sc[g], 2, 64);
    sc[g] *= 0.125f;                      // 1/sqrt(64)
  }
  float mx = sc[0];
#pragma unroll
  for (int g = 1; g < 16; ++g) mx = fmaxf(mx, sc[g]);
  float sum = 0.f;
#pragma unroll
  for (int g = 0; g < 16; ++g) { sc[g] = __expf(sc[g] - mx); sum += sc[g]; }
  const float inv = 1.f / sum;

  // lane (h,p) writes attn[h, p*4 .. p*4+3] (all p-lanes hold the full row)
  float4 w4;
  w4.x = (p == 0) ? sc[0] : (p == 1) ? sc[4] : (p == 2) ? sc[8]  : sc[12];
  w4.y = (p == 0) ? sc[1] : (p == 1) ? sc[5] : (p == 2) ? sc[9]  : sc[13];
  w4.z = (p == 0) ? sc[2] : (p == 1) ? sc[6] : (p == 2) ? sc[10] : sc[14];
  w4.w = (p == 0) ? sc[3] : (p == 1) ? sc[7] : (p == 2) ? sc[11] : sc[15];
  w4.x *= inv; w4.y *= inv; w4.z *= inv; w4.w *= inv;
  *(float4*)&pl[wave][h][p * 4] = w4;
  __syncthreads();

  // ---- phase 2: lane = d.  out[h,d] = sum_g attn[h,g] * V[g,d]
  float vf[16];
#pragma unroll
  for (int g = 0; g < 16; ++g) vf[g] = bf2f(V[base + g * 64 + lane]);

  uint32 ow[8];
#pragma unroll
  for (int jh = 0; jh < 16; ++jh) {
    const float4 a0 = *(const float4*)&pl[wave][jh][0];
    const float4 a1 = *(const float4*)&pl[wave][jh][4];
    const float4 a2 = *(const float4*)&pl[wave][jh][8];
    const float4 a3 = *(const float4*)&pl[wave][jh][12];
    float s = a0.x * vf[0]  + a0.y * vf[1]  + a0.z * vf[2]  + a0.w * vf[3]
            + a1.x * vf[4]  + a1.y * vf[5]  + a1.z * vf[6]  + a1.w * vf[7]
            + a2.x * vf[8]  + a2.y * vf[9]  + a2.z * vf[10] + a2.w * vf[11]
            + a3.x * vf[12] + a3.y * vf[13] + a3.z * vf[14] + a3.w * vf[15];
    const uint32 bb = f2bf(s);
    if (jh & 1) ow[jh >> 1] |= bb << 16; else ow[jh >> 1] = bb;
  }
  uint4* op = (uint4*)(O + base + lane * 16);   // idx = d*16 + h, coalesced
  op[0] = make_uint4(ow[0], ow[1], ow[2], ow[3]);
  op[1] = make_uint4(ow[4], ow[5], ow[6], ow[7]);
}

// ---------------- in-place LayerNorm over rows of 1024 ----------------
__global__ __launch_bounds__(256) void ln_kernel(
    float* __restrict__ Y, const float* __restrict__ gw,
    const float* __restrict__ gb) {
  float* y = Y + (size_t)blockIdx.x * 1024;
  const int tid = threadIdx.x;
  float4 v = ((const float4*)y)[tid];
  float s  = v.x + v.y + v.z + v.w;
  float s2 = v.x * v.x + v.y * v.y + v.z * v.z + v.w * v.w;
#pragma unroll
  for (int o = 32; o > 0; o >>= 1) {
    s  += __shfl_xor(s, o, 64);
    s2 += __shfl_xor(s2, o, 64);
  }
  __shared__ float rs[4], rq[4];
  const int wave = tid >> 6;
  if ((tid & 63) == 0) { rs[wave] = s; rq[wave] = s2; }
  __syncthreads();
  s  = rs[0] + rs[1] + rs[2] + rs[3];
  s2 = rq[0] + rq[1] + rq[2] + rq[3];
  const float mean = s * (1.f / 1024.f);
  const float var  = s2 * (1.f / 1024.f) - mean * mean;
  const float r = rsqrtf(var + 1e-5f);
  const float4 w = ((const float4*)gw)[tid];
  const float4 bb = ((const float4*)gb)[tid];
  float4 o;
  o.x = (v.x - mean) * r * w.x + bb.x;
  o.y = (v.y - mean) * r * w.y + bb.y;
  o.z = (v.z - mean) * r * w.z + bb.z;
  o.w = (v.w - mean) * r * w.w + bb.w;
  ((float4*)y)[tid] = o;
}

extern "C" void kernel_launch(void* const* d_in, const int* in_sizes, int n_in,
                              void* d_out, int out_size, void* d_ws,
                              size_t ws_size, hipStream_t stream) {
  const float* sa = (const float*)d_in[0];
  const float* st = (const float*)d_in[1];
  const float* Wq = (const float*)d_in[2];
  const float* bq = (const float*)d_in[3];
  const float* Wk = (const float*)d_in[4];
  const float* bk = (const float*)d_in[5];
  const float* Wv = (const float*)d_in[6];
  const float* bv = (const float*)d_in[7];
  const float* Wo = (const float*)d_in[8];
  const float* bo = (const float*)d_in[9];
  const float* lw = (const float*)d_in[10];
  const float* lb = (const float*)d_in[11];
  float* out = (float*)d_out;

  const int M = 32768, D = 1024;
  const size_t MiB = 1024 * 1024;
  char* w = (char*)d_ws;
  unsigned short* saB = (unsigned short*)(w);                // 64 MiB
  unsigned short* stB = (unsigned short*)(w + 64 * MiB);     // 64 MiB
  unsigned short* WqB = (unsigned short*)(w + 128 * MiB);    // 2 MiB
  unsigned short* WkB = (unsigned short*)(w + 130 * MiB);
  unsigned short* WvB = (unsigned short*)(w + 132 * MiB);
  unsigned short* WoB = (unsigned short*)(w + 134 * MiB);
  unsigned short* Vb  = (unsigned short*)(w + 136 * MiB);    // 64 MiB -> ws = 200 MiB
  // Q and K live in d_out (128 MiB fp32) -- both dead before O-proj writes it.
  unsigned short* Qb = (unsigned short*)d_out;
  unsigned short* Kb = (unsigned short*)d_out + (size_t)M * D;
  unsigned short* attb = saB;  // sa_bf16 is dead after the Q GEMM

  const int nH8 = M * D / 8;   // 4,194,304
  const int nW8 = D * D / 8;   // 131,072
  cast_kernel<<<nH8 / 256, 256, 0, stream>>>(sa, saB, nH8);
  cast_kernel<<<nH8 / 256, 256, 0, stream>>>(st, stB, nH8);
  cast_kernel<<<nW8 / 256, 256, 0, stream>>>(Wq, WqB, nW8);
  cast_kernel<<<nW8 / 256, 256, 0, stream>>>(Wk, WkB, nW8);
  cast_kernel<<<nW8 / 256, 256, 0, stream>>>(Wv, WvB, nW8);
  cast_kernel<<<nW8 / 256, 256, 0, stream>>>(Wo, WoB, nW8);

  dim3 g(M / 128, D / 128);   // (256, 8), m-fastest
  gemm_bt<0><<<g, 256, 0, stream>>>(saB, WqB, bq, nullptr, Qb, nullptr, M, D, D);
  gemm_bt<0><<<g, 256, 0, stream>>>(stB, WkB, bk, nullptr, Kb, nullptr, M, D, D);
  gemm_bt<0><<<g, 256, 0, stream>>>(stB, WvB, bv, nullptr, Vb, nullptr, M, D, D);

  attn_kernel<<<M / 4, 256, 0, stream>>>(Qb, Kb, Vb, attb);

  gemm_bt<1><<<g, 256, 0, stream>>>(attb, WoB, bo, sa, nullptr, out, M, D, D);

  ln_kernel<<<M, 256, 0, stream>>>(out, lw, lb);
}

// Round 2
// 713.289 us; speedup vs baseline: 1.1296x; 1.1296x over previous
//
#include <hip/hip_runtime.h>

typedef unsigned int  uint32;
typedef float  f32x4  __attribute__((ext_vector_type(4)));
typedef __bf16 bf16x8 __attribute__((ext_vector_type(8)));

__device__ __forceinline__ float bf2f(unsigned int u) {
  return __builtin_bit_cast(float, u << 16);
}
__device__ __forceinline__ unsigned short f2bf(float f) {
  uint32 u = __builtin_bit_cast(uint32, f);
  u += 0x7fffu + ((u >> 16) & 1u);          // RNE
  return (unsigned short)(u >> 16);
}

__device__ __forceinline__ void gload_lds16(const void* g, void* l) {
  __builtin_amdgcn_global_load_lds(
      (const __attribute__((address_space(1))) void*)g,
      (__attribute__((address_space(3))) void*)l, 16, 0, 0);
}

// ---------------- fp32 -> bf16 cast (8 elems/thread) ----------------
__global__ __launch_bounds__(256) void cast_kernel(
    const float* __restrict__ x, unsigned short* __restrict__ y, int n8) {
  int i = blockIdx.x * 256 + threadIdx.x;
  if (i >= n8) return;
  const float4* xp = (const float4*)x;
  float4 a = xp[2 * i], b = xp[2 * i + 1];
  uint4 o;
  o.x = (uint32)f2bf(a.x) | ((uint32)f2bf(a.y) << 16);
  o.y = (uint32)f2bf(a.z) | ((uint32)f2bf(a.w) << 16);
  o.z = (uint32)f2bf(b.x) | ((uint32)f2bf(b.y) << 16);
  o.w = (uint32)f2bf(b.z) | ((uint32)f2bf(b.w) << 16);
  ((uint4*)y)[i] = o;
}

// ------- bf16 GEMM: C[M,N] = A[M,K] * W[N,K]^T + bias -------
// 256x256 tile, BK=64, 8 waves (2M x 4N), double-buffered LDS with
// counted vmcnt(8) prefetch + XOR-swizzled LDS (conflict-free ds_read_b128).
// EPI=0: bf16 out.  EPI=1: fp32 out = acc + bias + resid.
template <int EPI>
__global__ __launch_bounds__(512, 2) void gemm256(
    const unsigned short* __restrict__ A, const unsigned short* __restrict__ W,
    const float* __restrict__ bias, const float* __restrict__ resid,
    unsigned short* __restrict__ Ob, float* __restrict__ Of,
    int M, int N, int K) {
  __shared__ char smem[131072];  // [2 dbuf][A 32KB | B 32KB]
  const int tid  = threadIdx.x;
  const int lane = tid & 63;
  const int wave = tid >> 6;      // 0..7
  const int wr   = wave >> 2;     // 0..1 : m half (128 rows)
  const int wc   = wave & 3;      // 0..3 : n quarter (64 cols)

  // XCD-aware bijective swizzle (nwg % 8 == 0), m-fastest layout.
  const int nwg  = gridDim.x;
  const int swz  = (blockIdx.x & 7) * (nwg >> 3) + (blockIdx.x >> 3);
  const int MB   = M >> 8;
  const int m0   = (swz % MB) << 8;
  const int n0   = (swz / MB) << 8;

  f32x4 acc[8][4];
#pragma unroll
  for (int m = 0; m < 8; ++m)
#pragma unroll
    for (int n = 0; n < 4; ++n) acc[m][n] = (f32x4)0.0f;

  // ---- staging geometry: per round r (0..3): 64 rows, this thread does
  // row = r*64 + wave*8 + (lane>>3), global col8 = (lane&7) ^ (lane>>3)
  // (inverse swizzle on the SOURCE; LDS dest stays linear: base + lane*16B).
  const int srow  = wave * 8 + (lane >> 3);
  const int scol8 = ((lane & 7) ^ (lane >> 3)) * 8;
  const unsigned short* Asrc = A + (size_t)(m0 + srow) * K + scol8;
  const unsigned short* Wsrc = W + (size_t)(n0 + srow) * K + scol8;
  const int ldsw = wave * 1024;  // wave-uniform byte base within a round

#define STAGE(dst, kt)                                                        \
  {                                                                           \
    const int kk = (kt) * 64;                                                 \
    _Pragma("unroll") for (int r = 0; r < 4; ++r) {                           \
      gload_lds16(Asrc + (size_t)(r * 64) * K + kk,                           \
                  smem + (dst) * 65536 + r * 8192 + ldsw);                    \
      gload_lds16(Wsrc + (size_t)(r * 64) * K + kk,                           \
                  smem + (dst) * 65536 + 32768 + r * 8192 + ldsw);            \
    }                                                                         \
  }

  // ---- fragment read geometry (swizzled): byte = row*128 + (kb ^ ((row&7)<<4))
  const int fr   = lane & 15;
  const int koff = (lane >> 4) * 16;      // k-byte within 64-byte half
  const int xorv = (fr & 7) << 4;         // row&7 == fr&7 for all frags

#define COMPUTE(cur)                                                          \
  {                                                                           \
    const char* aB = smem + (cur) * 65536;                                    \
    const char* bB = smem + (cur) * 65536 + 32768;                            \
    _Pragma("unroll") for (int ks = 0; ks < 2; ++ks) {                        \
      const int kb = ((ks << 6) | koff) ^ xorv;                               \
      bf16x8 av[8], bv[4];                                                    \
      _Pragma("unroll") for (int m = 0; m < 8; ++m)                           \
          av[m] = *(const bf16x8*)(aB + (wr * 128 + m * 16 + fr) * 128 + kb); \
      _Pragma("unroll") for (int n = 0; n < 4; ++n)                           \
          bv[n] = *(const bf16x8*)(bB + (wc * 64 + n * 16 + fr) * 128 + kb);  \
      _Pragma("unroll") for (int m = 0; m < 8; ++m)                           \
          _Pragma("unroll") for (int n = 0; n < 4; ++n)                       \
              acc[m][n] = __builtin_amdgcn_mfma_f32_16x16x32_bf16(            \
                  av[m], bv[n], acc[m][n], 0, 0, 0);                          \
    }                                                                         \
  }

  const int nt = K >> 6;  // 16
  STAGE(0, 0);
  for (int t = 0; t < nt - 1; ++t) {
    const int cur = t & 1;
    STAGE(cur ^ 1, t + 1);
    // tile t's 8 loads drained (8 newest = tile t+1 stay in flight)
    asm volatile("s_waitcnt vmcnt(8)\n\ts_barrier" ::: "memory");
    COMPUTE(cur);
    // reads complete (lgkm only -- keep prefetch in flight) before overwrite
    asm volatile("s_waitcnt lgkmcnt(0)\n\ts_barrier" ::: "memory");
  }
  asm volatile("s_waitcnt vmcnt(0)\n\ts_barrier" ::: "memory");
  COMPUTE((nt - 1) & 1);

  // ---- epilogue: C/D frag mapping col = lane&15, row = (lane>>4)*4 + i
  const int r4 = (lane >> 4) * 4;
#pragma unroll
  for (int n = 0; n < 4; ++n) {
    const int col = n0 + wc * 64 + n * 16 + fr;
    const float bvv = bias[col];
#pragma unroll
    for (int m = 0; m < 8; ++m) {
      const int row = m0 + wr * 128 + m * 16 + r4;
#pragma unroll
      for (int i = 0; i < 4; ++i) {
        const size_t idx = (size_t)(row + i) * N + col;
        float v = acc[m][n][i] + bvv;
        if constexpr (EPI == 0) {
          Ob[idx] = f2bf(v);
        } else {
          Of[idx] = v + resid[idx];
        }
      }
    }
  }
#undef STAGE
#undef COMPUTE
}

// ---------------- head-wise attention, one wave per row b ----------------
// Q,K,V: [B, 16 heads, 64 dims] bf16.  Out: [B, 1024] with idx = d*16 + h.
__global__ __launch_bounds__(256) void attn_kernel(
    const unsigned short* __restrict__ Q, const unsigned short* __restrict__ K,
    const unsigned short* __restrict__ V, unsigned short* __restrict__ O) {
  __shared__ float pl[4][16][16];
  const int tid  = threadIdx.x;
  const int lane = tid & 63;
  const int wave = tid >> 6;
  const int b = blockIdx.x * 4 + wave;
  const int h = lane >> 2, p = lane & 3;
  const size_t base = (size_t)b * 1024;

  float qf[16], kf[16];
  {
    const uint4* qp = (const uint4*)(Q + base + h * 64 + p * 16);
    const uint4* kp = (const uint4*)(K + base + h * 64 + p * 16);
    uint4 v0 = qp[0], v1 = qp[1];
    qf[0] = bf2f(v0.x & 0xffff); qf[1] = bf2f(v0.x >> 16);
    qf[2] = bf2f(v0.y & 0xffff); qf[3] = bf2f(v0.y >> 16);
    qf[4] = bf2f(v0.z & 0xffff); qf[5] = bf2f(v0.z >> 16);
    qf[6] = bf2f(v0.w & 0xffff); qf[7] = bf2f(v0.w >> 16);
    qf[8]  = bf2f(v1.x & 0xffff); qf[9]  = bf2f(v1.x >> 16);
    qf[10] = bf2f(v1.y & 0xffff); qf[11] = bf2f(v1.y >> 16);
    qf[12] = bf2f(v1.z & 0xffff); qf[13] = bf2f(v1.z >> 16);
    qf[14] = bf2f(v1.w & 0xffff); qf[15] = bf2f(v1.w >> 16);
    uint4 k0 = kp[0], k1 = kp[1];
    kf[0] = bf2f(k0.x & 0xffff); kf[1] = bf2f(k0.x >> 16);
    kf[2] = bf2f(k0.y & 0xffff); kf[3] = bf2f(k0.y >> 16);
    kf[4] = bf2f(k0.z & 0xffff); kf[5] = bf2f(k0.z >> 16);
    kf[6] = bf2f(k0.w & 0xffff); kf[7] = bf2f(k0.w >> 16);
    kf[8]  = bf2f(k1.x & 0xffff); kf[9]  = bf2f(k1.x >> 16);
    kf[10] = bf2f(k1.y & 0xffff); kf[11] = bf2f(k1.y >> 16);
    kf[12] = bf2f(k1.z & 0xffff); kf[13] = bf2f(k1.z >> 16);
    kf[14] = bf2f(k1.w & 0xffff); kf[15] = bf2f(k1.w >> 16);
  }

  float sc[16];
#pragma unroll
  for (int g = 0; g < 16; ++g) {
    const int src = g * 4 + p;
    float s = 0.f;
#pragma unroll
    for (int j = 0; j < 16; ++j) s += qf[j] * __shfl(kf[j], src, 64);
    sc[g] = s;
  }
#pragma unroll
  for (int g = 0; g < 16; ++g) {
    sc[g] += __shfl_xor(sc[g], 1, 64);
    sc[g] += __shfl_xor(sc[g], 2, 64);
    sc[g] *= 0.125f;                      // 1/sqrt(64)
  }
  float mx = sc[0];
#pragma unroll
  for (int g = 1; g < 16; ++g) mx = fmaxf(mx, sc[g]);
  float sum = 0.f;
#pragma unroll
  for (int g = 0; g < 16; ++g) { sc[g] = __expf(sc[g] - mx); sum += sc[g]; }
  const float inv = 1.f / sum;

  float4 w4;
  w4.x = (p == 0) ? sc[0] : (p == 1) ? sc[4] : (p == 2) ? sc[8]  : sc[12];
  w4.y = (p == 0) ? sc[1] : (p == 1) ? sc[5] : (p == 2) ? sc[9]  : sc[13];
  w4.z = (p == 0) ? sc[2] : (p == 1) ? sc[6] : (p == 2) ? sc[10] : sc[14];
  w4.w = (p == 0) ? sc[3] : (p == 1) ? sc[7] : (p == 2) ? sc[11] : sc[15];
  w4.x *= inv; w4.y *= inv; w4.z *= inv; w4.w *= inv;
  *(float4*)&pl[wave][h][p * 4] = w4;
  __syncthreads();

  float vf[16];
#pragma unroll
  for (int g = 0; g < 16; ++g) vf[g] = bf2f(V[base + g * 64 + lane]);

  uint32 ow[8];
#pragma unroll
  for (int jh = 0; jh < 16; ++jh) {
    const float4 a0 = *(const float4*)&pl[wave][jh][0];
    const float4 a1 = *(const float4*)&pl[wave][jh][4];
    const float4 a2 = *(const float4*)&pl[wave][jh][8];
    const float4 a3 = *(const float4*)&pl[wave][jh][12];
    float s = a0.x * vf[0]  + a0.y * vf[1]  + a0.z * vf[2]  + a0.w * vf[3]
            + a1.x * vf[4]  + a1.y * vf[5]  + a1.z * vf[6]  + a1.w * vf[7]
            + a2.x * vf[8]  + a2.y * vf[9]  + a2.z * vf[10] + a2.w * vf[11]
            + a3.x * vf[12] + a3.y * vf[13] + a3.z * vf[14] + a3.w * vf[15];
    const uint32 bb = f2bf(s);
    if (jh & 1) ow[jh >> 1] |= bb << 16; else ow[jh >> 1] = bb;
  }
  uint4* op = (uint4*)(O + base + lane * 16);   // idx = d*16 + h, coalesced
  op[0] = make_uint4(ow[0], ow[1], ow[2], ow[3]);
  op[1] = make_uint4(ow[4], ow[5], ow[6], ow[7]);
}

// ---------------- in-place LayerNorm over rows of 1024 ----------------
__global__ __launch_bounds__(256) void ln_kernel(
    float* __restrict__ Y, const float* __restrict__ gw,
    const float* __restrict__ gb) {
  float* y = Y + (size_t)blockIdx.x * 1024;
  const int tid = threadIdx.x;
  float4 v = ((const float4*)y)[tid];
  float s  = v.x + v.y + v.z + v.w;
  float s2 = v.x * v.x + v.y * v.y + v.z * v.z + v.w * v.w;
#pragma unroll
  for (int o = 32; o > 0; o >>= 1) {
    s  += __shfl_xor(s, o, 64);
    s2 += __shfl_xor(s2, o, 64);
  }
  __shared__ float rs[4], rq[4];
  const int wave = tid >> 6;
  if ((tid & 63) == 0) { rs[wave] = s; rq[wave] = s2; }
  __syncthreads();
  s  = rs[0] + rs[1] + rs[2] + rs[3];
  s2 = rq[0] + rq[1] + rq[2] + rq[3];
  const float mean = s * (1.f / 1024.f);
  const float var  = s2 * (1.f / 1024.f) - mean * mean;
  const float r = rsqrtf(var + 1e-5f);
  const float4 w = ((const float4*)gw)[tid];
  const float4 bb = ((const float4*)gb)[tid];
  float4 o;
  o.x = (v.x - mean) * r * w.x + bb.x;
  o.y = (v.y - mean) * r * w.y + bb.y;
  o.z = (v.z - mean) * r * w.z + bb.z;
  o.w = (v.w - mean) * r * w.w + bb.w;
  ((float4*)y)[tid] = o;
}

extern "C" void kernel_launch(void* const* d_in, const int* in_sizes, int n_in,
                              void* d_out, int out_size, void* d_ws,
                              size_t ws_size, hipStream_t stream) {
  const float* sa = (const float*)d_in[0];
  const float* st = (const float*)d_in[1];
  const float* Wq = (const float*)d_in[2];
  const float* bq = (const float*)d_in[3];
  const float* Wk = (const float*)d_in[4];
  const float* bk = (const float*)d_in[5];
  const float* Wv = (const float*)d_in[6];
  const float* bv = (const float*)d_in[7];
  const float* Wo = (const float*)d_in[8];
  const float* bo = (const float*)d_in[9];
  const float* lw = (const float*)d_in[10];
  const float* lb = (const float*)d_in[11];
  float* out = (float*)d_out;

  const int M = 32768, D = 1024;
  const size_t MiB = 1024 * 1024;
  char* w = (char*)d_ws;
  unsigned short* saB = (unsigned short*)(w);                // 64 MiB
  unsigned short* stB = (unsigned short*)(w + 64 * MiB);     // 64 MiB
  unsigned short* WqB = (unsigned short*)(w + 128 * MiB);    // 2 MiB
  unsigned short* WkB = (unsigned short*)(w + 130 * MiB);
  unsigned short* WvB = (unsigned short*)(w + 132 * MiB);
  unsigned short* WoB = (unsigned short*)(w + 134 * MiB);
  unsigned short* Vb  = (unsigned short*)(w + 136 * MiB);    // 64 MiB -> ws = 200 MiB
  // Q and K live in d_out (128 MiB fp32) -- both dead before O-proj writes it.
  unsigned short* Qb = (unsigned short*)d_out;
  unsigned short* Kb = (unsigned short*)d_out + (size_t)M * D;
  unsigned short* attb = saB;  // sa_bf16 is dead after the Q GEMM

  const int nH8 = M * D / 8;
  const int nW8 = D * D / 8;
  cast_kernel<<<nH8 / 256, 256, 0, stream>>>(sa, saB, nH8);
  cast_kernel<<<nH8 / 256, 256, 0, stream>>>(st, stB, nH8);
  cast_kernel<<<nW8 / 256, 256, 0, stream>>>(Wq, WqB, nW8);
  cast_kernel<<<nW8 / 256, 256, 0, stream>>>(Wk, WkB, nW8);
  cast_kernel<<<nW8 / 256, 256, 0, stream>>>(Wv, WvB, nW8);
  cast_kernel<<<nW8 / 256, 256, 0, stream>>>(Wo, WoB, nW8);

  const int nblk = (M / 256) * (D / 256);   // 512
  gemm256<0><<<nblk, 512, 0, stream>>>(saB, WqB, bq, nullptr, Qb, nullptr, M, D, D);
  gemm256<0><<<nblk, 512, 0, stream>>>(stB, WkB, bk, nullptr, Kb, nullptr, M, D, D);
  gemm256<0><<<nblk, 512, 0, stream>>>(stB, WvB, bv, nullptr, Vb, nullptr, M, D, D);

  attn_kernel<<<M / 4, 256, 0, stream>>>(Qb, Kb, Vb, attb);

  gemm256<1><<<nblk, 512, 0, stream>>>(attb, WoB, bo, sa, nullptr, out, M, D, D);

  ln_kernel<<<M, 256, 0, stream>>>(out, lw, lb);
}

// Round 4
// 652.743 us; speedup vs baseline: 1.2344x; 1.0928x over previous
//
#include <hip/hip_runtime.h>

typedef unsigned int  uint32;
typedef float  f32x4  __attribute__((ext_vector_type(4)));
typedef __bf16 bf16x8 __attribute__((ext_vector_type(8)));

__device__ __forceinline__ float bf2f(unsigned int u) {
  return __builtin_bit_cast(float, u << 16);
}
__device__ __forceinline__ unsigned short f2bf(float f) {
  uint32 u = __builtin_bit_cast(uint32, f);
  u += 0x7fffu + ((u >> 16) & 1u);          // RNE
  return (unsigned short)(u >> 16);
}

__device__ __forceinline__ void gload_lds16(const void* g, void* l) {
  __builtin_amdgcn_global_load_lds(
      (const __attribute__((address_space(1))) void*)g,
      (__attribute__((address_space(3))) void*)l, 16, 0, 0);
}

// ---------------- fp32 -> bf16 cast (8 elems/thread) ----------------
__global__ __launch_bounds__(256) void cast_kernel(
    const float* __restrict__ x, unsigned short* __restrict__ y, int n8) {
  int i = blockIdx.x * 256 + threadIdx.x;
  if (i >= n8) return;
  const float4* xp = (const float4*)x;
  float4 a = xp[2 * i], b = xp[2 * i + 1];
  uint4 o;
  o.x = (uint32)f2bf(a.x) | ((uint32)f2bf(a.y) << 16);
  o.y = (uint32)f2bf(a.z) | ((uint32)f2bf(a.w) << 16);
  o.z = (uint32)f2bf(b.x) | ((uint32)f2bf(b.y) << 16);
  o.w = (uint32)f2bf(b.z) | ((uint32)f2bf(b.w) << 16);
  ((uint4*)y)[i] = o;
}

// ------- bf16 GEMM: C[M,N] = A[M,K] * W[N,K]^T + bias -------
// 256x256 tile, BK=32, 8 waves (2M x 4N), FOUR LDS buffers, 3-tile-deep
// prefetch with counted vmcnt(8) (= 4 loads/tile x 2 tiles ahead in flight),
// raw s_barrier, paired-row XOR swizzle.
// LDS logical row r (256 rows x 32 bf16 = 64B) stored at:
//   byte = (r>>1)*128 + (((r&1)*4 + kb16) ^ ((r>>1)&7))*16 + (kb&15)
// EPI=0: bf16 out.  EPI=1: fp32 out = acc + bias + resid.
template <int EPI>
__global__ __launch_bounds__(512, 2) void gemm256(
    const unsigned short* __restrict__ A, const unsigned short* __restrict__ W,
    const float* __restrict__ bias, const float* __restrict__ resid,
    unsigned short* __restrict__ Ob, float* __restrict__ Of,
    int M, int N, int K) {
  __shared__ char smem[131072];  // 4 bufs x (A 16KB | B 16KB)
  const int tid  = threadIdx.x;
  const int lane = tid & 63;
  const int wave = tid >> 6;      // 0..7
  const int wr   = wave >> 2;     // 0..1 : m half (128 rows)
  const int wc   = wave & 3;      // 0..3 : n quarter (64 cols)

  // XCD-aware bijective swizzle (nwg % 8 == 0), m-fastest layout.
  const int nwg  = gridDim.x;
  const int swz  = (blockIdx.x & 7) * (nwg >> 3) + (blockIdx.x >> 3);
  const int MB   = M >> 8;
  const int m0   = (swz % MB) << 8;
  const int n0   = (swz / MB) << 8;

  f32x4 acc[8][4];
#pragma unroll
  for (int m = 0; m < 8; ++m)
#pragma unroll
    for (int n = 0; n < 4; ++n) acc[m][n] = (f32x4)0.0f;

  // ---- staging geometry (inverse-swizzled global source, linear LDS dest).
  // Unit u (= wave*2 + l) covers logical rows [u*16, u*16+16), 16KB region
  // dest byte = u*1024 + lane*16  ->  phys row u*8 + (lane>>3), chunk lane&7.
  const int pr8 = lane >> 3;                 // phys row within unit
  const int cl  = (lane & 7) ^ pr8;          // logical chunk (inverse swizzle)
  const int rA0 = (wave * 2) * 16 + pr8 * 2 + (cl >> 2);  // logical row, unit w*2
  const int kb8 = (cl & 3) * 8;              // k-elem offset 0/8/16/24
  const unsigned short* As0 = A + (size_t)(m0 + rA0) * K + kb8;
  const unsigned short* As1 = As0 + (size_t)16 * K;
  const unsigned short* Bs0 = W + (size_t)(n0 + rA0) * K + kb8;
  const unsigned short* Bs1 = Bs0 + (size_t)16 * K;
  const int dA = wave * 2048 + lane * 16;

#define STAGE(d, kt)                                                          \
  {                                                                           \
    char* sb = smem + (d) * 32768;                                            \
    const int ko = (kt) * 32;                                                 \
    gload_lds16(As0 + ko, sb + dA);                                           \
    gload_lds16(As1 + ko, sb + dA + 1024);                                    \
    gload_lds16(Bs0 + ko, sb + 16384 + dA);                                   \
    gload_lds16(Bs1 + ko, sb + 16384 + dA + 1024);                            \
  }

  // ---- fragment read offsets (swizzled), conflict-free (2 lanes/bank-quad).
  const int fr  = lane & 15, kg = lane >> 4, frh = fr >> 1;
  const int cA  = ((((fr & 1) * 4) + kg) ^ frh) * 16;
  const int aoff = (wr * 64 + frh) * 128 + cA;            // + m*1024
  const int boff = 16384 + (wc * 32 + frh) * 128 + cA;    // + n*1024

#define MFMAS(base_)                                                          \
  {                                                                           \
    bf16x8 av[8], bv[4];                                                      \
    _Pragma("unroll") for (int m = 0; m < 8; ++m)                             \
        av[m] = *(const bf16x8*)((base_) + aoff + m * 1024);                  \
    _Pragma("unroll") for (int n = 0; n < 4; ++n)                             \
        bv[n] = *(const bf16x8*)((base_) + boff + n * 1024);                  \
    __builtin_amdgcn_s_setprio(1);                                            \
    _Pragma("unroll") for (int m = 0; m < 8; ++m)                             \
        _Pragma("unroll") for (int n = 0; n < 4; ++n)                         \
            acc[m][n] = __builtin_amdgcn_mfma_f32_16x16x32_bf16(              \
                av[m], bv[n], acc[m][n], 0, 0, 0);                            \
    __builtin_amdgcn_s_setprio(0);                                            \
  }

  const int nt = K >> 5;  // 32 K-tiles
  STAGE(0, 0);
  STAGE(1, 1);
  STAGE(2, 2);

  for (int t = 0; t < nt - 3; ++t) {
    // Drain until only tiles t+1,t+2 (2 tiles x 4 loads = 8) remain in
    // flight -> tile t's loads (oldest, in-order retire) have landed.
    asm volatile("s_waitcnt vmcnt(8)" ::: "memory");
    __builtin_amdgcn_s_barrier();
    const char* base = smem + (t & 3) * 32768;
    bf16x8 av[8], bv[4];
#pragma unroll
    for (int m = 0; m < 8; ++m)
      av[m] = *(const bf16x8*)(base + aoff + m * 1024);
#pragma unroll
    for (int n = 0; n < 4; ++n)
      bv[n] = *(const bf16x8*)(base + boff + n * 1024);
    STAGE((t + 3) & 3, t + 3);   // into buffer freed at end of iter t-1
    __builtin_amdgcn_s_setprio(1);
#pragma unroll
    for (int m = 0; m < 8; ++m)
#pragma unroll
      for (int n = 0; n < 4; ++n)
        acc[m][n] = __builtin_amdgcn_mfma_f32_16x16x32_bf16(av[m], bv[n],
                                                            acc[m][n], 0, 0, 0);
    __builtin_amdgcn_s_setprio(0);
    // all my ds_reads of buf t&3 done -> buffer reusable after barrier
    asm volatile("s_waitcnt lgkmcnt(0)" ::: "memory");
    __builtin_amdgcn_s_barrier();
  }
  // tail: tiles nt-3, nt-2, nt-1 (no more staging)
  asm volatile("s_waitcnt vmcnt(8)" ::: "memory");
  __builtin_amdgcn_s_barrier();
  MFMAS(smem + ((nt - 3) & 3) * 32768);
  asm volatile("s_waitcnt vmcnt(4)" ::: "memory");
  __builtin_amdgcn_s_barrier();
  MFMAS(smem + ((nt - 2) & 3) * 32768);
  asm volatile("s_waitcnt vmcnt(0)" ::: "memory");
  __builtin_amdgcn_s_barrier();
  MFMAS(smem + ((nt - 1) & 3) * 32768);

  // ---- epilogue: C/D frag mapping col = lane&15, row = (lane>>4)*4 + i
  const int r4 = (lane >> 4) * 4;
#pragma unroll
  for (int n = 0; n < 4; ++n) {
    const int col = n0 + wc * 64 + n * 16 + fr;
    const float bvv = bias[col];
#pragma unroll
    for (int m = 0; m < 8; ++m) {
      const int row = m0 + wr * 128 + m * 16 + r4;
#pragma unroll
      for (int i = 0; i < 4; ++i) {
        const size_t idx = (size_t)(row + i) * N + col;
        float v = acc[m][n][i] + bvv;
        if constexpr (EPI == 0) {
          Ob[idx] = f2bf(v);
        } else {
          Of[idx] = v + resid[idx];
        }
      }
    }
  }
#undef STAGE
#undef MFMAS
}

// ---------------- head-wise attention, one wave per row b ----------------
// Q,K,V: [B, 16 heads, 64 dims] bf16.  Out: [B, 1024] with idx = d*16 + h.
__global__ __launch_bounds__(256) void attn_kernel(
    const unsigned short* __restrict__ Q, const unsigned short* __restrict__ K,
    const unsigned short* __restrict__ V, unsigned short* __restrict__ O) {
  __shared__ float pl[4][16][16];
  const int tid  = threadIdx.x;
  const int lane = tid & 63;
  const int wave = tid >> 6;
  const int b = blockIdx.x * 4 + wave;
  const int h = lane >> 2, p = lane & 3;
  const size_t base = (size_t)b * 1024;

  float qf[16], kf[16];
  {
    const uint4* qp = (const uint4*)(Q + base + h * 64 + p * 16);
    const uint4* kp = (const uint4*)(K + base + h * 64 + p * 16);
    uint4 v0 = qp[0], v1 = qp[1];
    qf[0] = bf2f(v0.x & 0xffff); qf[1] = bf2f(v0.x >> 16);
    qf[2] = bf2f(v0.y & 0xffff); qf[3] = bf2f(v0.y >> 16);
    qf[4] = bf2f(v0.z & 0xffff); qf[5] = bf2f(v0.z >> 16);
    qf[6] = bf2f(v0.w & 0xffff); qf[7] = bf2f(v0.w >> 16);
    qf[8]  = bf2f(v1.x & 0xffff); qf[9]  = bf2f(v1.x >> 16);
    qf[10] = bf2f(v1.y & 0xffff); qf[11] = bf2f(v1.y >> 16);
    qf[12] = bf2f(v1.z & 0xffff); qf[13] = bf2f(v1.z >> 16);
    qf[14] = bf2f(v1.w & 0xffff); qf[15] = bf2f(v1.w >> 16);
    uint4 k0 = kp[0], k1 = kp[1];
    kf[0] = bf2f(k0.x & 0xffff); kf[1] = bf2f(k0.x >> 16);
    kf[2] = bf2f(k0.y & 0xffff); kf[3] = bf2f(k0.y >> 16);
    kf[4] = bf2f(k0.z & 0xffff); kf[5] = bf2f(k0.z >> 16);
    kf[6] = bf2f(k0.w & 0xffff); kf[7] = bf2f(k0.w >> 16);
    kf[8]  = bf2f(k1.x & 0xffff); kf[9]  = bf2f(k1.x >> 16);
    kf[10] = bf2f(k1.y & 0xffff); kf[11] = bf2f(k1.y >> 16);
    kf[12] = bf2f(k1.z & 0xffff); kf[13] = bf2f(k1.z >> 16);
    kf[14] = bf2f(k1.w & 0xffff); kf[15] = bf2f(k1.w >> 16);
  }

  float sc[16];
#pragma unroll
  for (int g = 0; g < 16; ++g) {
    const int src = g * 4 + p;
    float s = 0.f;
#pragma unroll
    for (int j = 0; j < 16; ++j) s += qf[j] * __shfl(kf[j], src, 64);
    sc[g] = s;
  }
#pragma unroll
  for (int g = 0; g < 16; ++g) {
    sc[g] += __shfl_xor(sc[g], 1, 64);
    sc[g] += __shfl_xor(sc[g], 2, 64);
    sc[g] *= 0.125f;                      // 1/sqrt(64)
  }
  float mx = sc[0];
#pragma unroll
  for (int g = 1; g < 16; ++g) mx = fmaxf(mx, sc[g]);
  float sum = 0.f;
#pragma unroll
  for (int g = 0; g < 16; ++g) { sc[g] = __expf(sc[g] - mx); sum += sc[g]; }
  const float inv = 1.f / sum;

  float4 w4;
  w4.x = (p == 0) ? sc[0] : (p == 1) ? sc[4] : (p == 2) ? sc[8]  : sc[12];
  w4.y = (p == 0) ? sc[1] : (p == 1) ? sc[5] : (p == 2) ? sc[9]  : sc[13];
  w4.z = (p == 0) ? sc[2] : (p == 1) ? sc[6] : (p == 2) ? sc[10] : sc[14];
  w4.w = (p == 0) ? sc[3] : (p == 1) ? sc[7] : (p == 2) ? sc[11] : sc[15];
  w4.x *= inv; w4.y *= inv; w4.z *= inv; w4.w *= inv;
  *(float4*)&pl[wave][h][p * 4] = w4;
  __syncthreads();

  float vf[16];
#pragma unroll
  for (int g = 0; g < 16; ++g) vf[g] = bf2f(V[base + g * 64 + lane]);

  uint32 ow[8];
#pragma unroll
  for (int jh = 0; jh < 16; ++jh) {
    const float4 a0 = *(const float4*)&pl[wave][jh][0];
    const float4 a1 = *(const float4*)&pl[wave][jh][4];
    const float4 a2 = *(const float4*)&pl[wave][jh][8];
    const float4 a3 = *(const float4*)&pl[wave][jh][12];
    float s = a0.x * vf[0]  + a0.y * vf[1]  + a0.z * vf[2]  + a0.w * vf[3]
            + a1.x * vf[4]  + a1.y * vf[5]  + a1.z * vf[6]  + a1.w * vf[7]
            + a2.x * vf[8]  + a2.y * vf[9]  + a2.z * vf[10] + a2.w * vf[11]
            + a3.x * vf[12] + a3.y * vf[13] + a3.z * vf[14] + a3.w * vf[15];
    const uint32 bb = f2bf(s);
    if (jh & 1) ow[jh >> 1] |= bb << 16; else ow[jh >> 1] = bb;
  }
  uint4* op = (uint4*)(O + base + lane * 16);   // idx = d*16 + h, coalesced
  op[0] = make_uint4(ow[0], ow[1], ow[2], ow[3]);
  op[1] = make_uint4(ow[4], ow[5], ow[6], ow[7]);
}

// ---------------- in-place LayerNorm over rows of 1024 ----------------
__global__ __launch_bounds__(256) void ln_kernel(
    float* __restrict__ Y, const float* __restrict__ gw,
    const float* __restrict__ gb) {
  float* y = Y + (size_t)blockIdx.x * 1024;
  const int tid = threadIdx.x;
  float4 v = ((const float4*)y)[tid];
  float s  = v.x + v.y + v.z + v.w;
  float s2 = v.x * v.x + v.y * v.y + v.z * v.z + v.w * v.w;
#pragma unroll
  for (int o = 32; o > 0; o >>= 1) {
    s  += __shfl_xor(s, o, 64);
    s2 += __shfl_xor(s2, o, 64);
  }
  __shared__ float rs[4], rq[4];
  const int wave = tid >> 6;
  if ((tid & 63) == 0) { rs[wave] = s; rq[wave] = s2; }
  __syncthreads();
  s  = rs[0] + rs[1] + rs[2] + rs[3];
  s2 = rq[0] + rq[1] + rq[2] + rq[3];
  const float mean = s * (1.f / 1024.f);
  const float var  = s2 * (1.f / 1024.f) - mean * mean;
  const float r = rsqrtf(var + 1e-5f);
  const float4 w = ((const float4*)gw)[tid];
  const float4 bb = ((const float4*)gb)[tid];
  float4 o;
  o.x = (v.x - mean) * r * w.x + bb.x;
  o.y = (v.y - mean) * r * w.y + bb.y;
  o.z = (v.z - mean) * r * w.z + bb.z;
  o.w = (v.w - mean) * r * w.w + bb.w;
  ((float4*)y)[tid] = o;
}

extern "C" void kernel_launch(void* const* d_in, const int* in_sizes, int n_in,
                              void* d_out, int out_size, void* d_ws,
                              size_t ws_size, hipStream_t stream) {
  const float* sa = (const float*)d_in[0];
  const float* st = (const float*)d_in[1];
  const float* Wq = (const float*)d_in[2];
  const float* bq = (const float*)d_in[3];
  const float* Wk = (const float*)d_in[4];
  const float* bk = (const float*)d_in[5];
  const float* Wv = (const float*)d_in[6];
  const float* bv = (const float*)d_in[7];
  const float* Wo = (const float*)d_in[8];
  const float* bo = (const float*)d_in[9];
  const float* lw = (const float*)d_in[10];
  const float* lb = (const float*)d_in[11];
  float* out = (float*)d_out;

  const int M = 32768, D = 1024;
  const size_t MiB = 1024 * 1024;
  char* w = (char*)d_ws;
  unsigned short* saB = (unsigned short*)(w);                // 64 MiB
  unsigned short* stB = (unsigned short*)(w + 64 * MiB);     // 64 MiB
  unsigned short* WqB = (unsigned short*)(w + 128 * MiB);    // 2 MiB
  unsigned short* WkB = (unsigned short*)(w + 130 * MiB);
  unsigned short* WvB = (unsigned short*)(w + 132 * MiB);
  unsigned short* WoB = (unsigned short*)(w + 134 * MiB);
  unsigned short* Vb  = (unsigned short*)(w + 136 * MiB);    // 64 MiB -> ws = 200 MiB
  // Q and K live in d_out (128 MiB fp32) -- both dead before O-proj writes it.
  unsigned short* Qb = (unsigned short*)d_out;
  unsigned short* Kb = (unsigned short*)d_out + (size_t)M * D;
  unsigned short* attb = saB;  // sa_bf16 is dead after the Q GEMM

  const int nH8 = M * D / 8;
  const int nW8 = D * D / 8;
  cast_kernel<<<nH8 / 256, 256, 0, stream>>>(sa, saB, nH8);
  cast_kernel<<<nH8 / 256, 256, 0, stream>>>(st, stB, nH8);
  cast_kernel<<<nW8 / 256, 256, 0, stream>>>(Wq, WqB, nW8);
  cast_kernel<<<nW8 / 256, 256, 0, stream>>>(Wk, WkB, nW8);
  cast_kernel<<<nW8 / 256, 256, 0, stream>>>(Wv, WvB, nW8);
  cast_kernel<<<nW8 / 256, 256, 0, stream>>>(Wo, WoB, nW8);

  const int nblk = (M / 256) * (D / 256);   // 512
  gemm256<0><<<nblk, 512, 0, stream>>>(saB, WqB, bq, nullptr, Qb, nullptr, M, D, D);
  gemm256<0><<<nblk, 512, 0, stream>>>(stB, WkB, bk, nullptr, Kb, nullptr, M, D, D);
  gemm256<0><<<nblk, 512, 0, stream>>>(stB, WvB, bv, nullptr, Vb, nullptr, M, D, D);

  attn_kernel<<<M / 4, 256, 0, stream>>>(Qb, Kb, Vb, attb);

  gemm256<1><<<nblk, 512, 0, stream>>>(attb, WoB, bo, sa, nullptr, out, M, D, D);

  ln_kernel<<<M, 256, 0, stream>>>(out, lw, lb);
}

// Round 5
// 564.897 us; speedup vs baseline: 1.4263x; 1.1555x over previous
//
#include <hip/hip_runtime.h>

typedef unsigned int  uint32;
typedef float  f32x4   __attribute__((ext_vector_type(4)));
typedef __bf16 bf16x8  __attribute__((ext_vector_type(8)));
typedef short  s16x4   __attribute__((ext_vector_type(4)));

__device__ __forceinline__ float bf2f(unsigned int u) {
  return __builtin_bit_cast(float, u << 16);
}
__device__ __forceinline__ unsigned short f2bf(float f) {
  uint32 u = __builtin_bit_cast(uint32, f);
  u += 0x7fffu + ((u >> 16) & 1u);          // RNE
  return (unsigned short)(u >> 16);
}

__device__ __forceinline__ void gload_lds16(const void* g, void* l) {
  __builtin_amdgcn_global_load_lds(
      (const __attribute__((address_space(1))) void*)g,
      (__attribute__((address_space(3))) void*)l, 16, 0, 0);
}

// ---------------- fp32 -> bf16 cast (8 elems/thread) ----------------
__global__ __launch_bounds__(256) void cast_kernel(
    const float* __restrict__ x, unsigned short* __restrict__ y, int n8) {
  int i = blockIdx.x * 256 + threadIdx.x;
  if (i >= n8) return;
  const float4* xp = (const float4*)x;
  float4 a = xp[2 * i], b = xp[2 * i + 1];
  uint4 o;
  o.x = (uint32)f2bf(a.x) | ((uint32)f2bf(a.y) << 16);
  o.y = (uint32)f2bf(a.z) | ((uint32)f2bf(a.w) << 16);
  o.z = (uint32)f2bf(b.x) | ((uint32)f2bf(b.y) << 16);
  o.w = (uint32)f2bf(b.z) | ((uint32)f2bf(b.w) << 16);
  ((uint4*)y)[i] = o;
}

// ------- bf16 GEMM: C[M,N] = A[M,K] * W[N,K]^T + bias -------
// 256x256 tile, BK=32, 8 waves (2M x 4N), FOUR LDS buffers, 3-tile-deep
// prefetch with counted vmcnt(8), raw s_barrier, paired-row XOR swizzle.
// Block mapping: XCD chunk = 16 m-tiles x 4 n-tiles, n-fastest, so
// co-resident blocks on one XCD share A-panels through that XCD's L2.
// EPI=0: bf16 out.  EPI=1: fp32 out = acc + bias + resid.
template <int EPI>
__global__ __launch_bounds__(512, 2) void gemm256(
    const unsigned short* __restrict__ A, const unsigned short* __restrict__ W,
    const float* __restrict__ bias, const float* __restrict__ resid,
    unsigned short* __restrict__ Ob, float* __restrict__ Of,
    int M, int N, int K) {
  __shared__ char smem[131072];  // 4 bufs x (A 16KB | B 16KB)
  const int tid  = threadIdx.x;
  const int lane = tid & 63;
  const int wave = tid >> 6;      // 0..7
  const int wr   = wave >> 2;     // 0..1 : m half (128 rows)
  const int wc   = wave & 3;      // 0..3 : n quarter (64 cols)

  // XCD chunk (bijective, nwg%8==0): n-fastest within chunk for A L2-reuse.
  const int nwg = gridDim.x;
  const int xcd = blockIdx.x & 7;
  const int r   = blockIdx.x >> 3;          // 0 .. nwg/8-1
  const int NT  = N >> 8;                   // n-tiles (4)
  const int m0  = (xcd * (nwg >> 3) / NT + r / NT) << 8;
  const int n0  = (r % NT) << 8;

  f32x4 acc[8][4];
#pragma unroll
  for (int m = 0; m < 8; ++m)
#pragma unroll
    for (int n = 0; n < 4; ++n) acc[m][n] = (f32x4)0.0f;

  // ---- staging geometry (inverse-swizzled global source, linear LDS dest).
  const int pr8 = lane >> 3;                 // phys row within unit
  const int cl  = (lane & 7) ^ pr8;          // logical chunk (inverse swizzle)
  const int rA0 = (wave * 2) * 16 + pr8 * 2 + (cl >> 2);
  const int kb8 = (cl & 3) * 8;              // k-elem offset 0/8/16/24
  const unsigned short* As0 = A + (size_t)(m0 + rA0) * K + kb8;
  const unsigned short* As1 = As0 + (size_t)16 * K;
  const unsigned short* Bs0 = W + (size_t)(n0 + rA0) * K + kb8;
  const unsigned short* Bs1 = Bs0 + (size_t)16 * K;
  const int dA = wave * 2048 + lane * 16;

#define STAGE(d, kt)                                                          \
  {                                                                           \
    char* sb = smem + (d) * 32768;                                            \
    const int ko = (kt) * 32;                                                 \
    gload_lds16(As0 + ko, sb + dA);                                           \
    gload_lds16(As1 + ko, sb + dA + 1024);                                    \
    gload_lds16(Bs0 + ko, sb + 16384 + dA);                                   \
    gload_lds16(Bs1 + ko, sb + 16384 + dA + 1024);                            \
  }

  // ---- fragment read offsets (swizzled), conflict-free (2 lanes/bank-quad).
  const int fr  = lane & 15, kg = lane >> 4, frh = fr >> 1;
  const int cA  = ((((fr & 1) * 4) + kg) ^ frh) * 16;
  const int aoff = (wr * 64 + frh) * 128 + cA;            // + m*1024
  const int boff = 16384 + (wc * 32 + frh) * 128 + cA;    // + n*1024

#define MFMAS(base_)                                                          \
  {                                                                           \
    bf16x8 av[8], bv[4];                                                      \
    _Pragma("unroll") for (int m = 0; m < 8; ++m)                             \
        av[m] = *(const bf16x8*)((base_) + aoff + m * 1024);                  \
    _Pragma("unroll") for (int n = 0; n < 4; ++n)                             \
        bv[n] = *(const bf16x8*)((base_) + boff + n * 1024);                  \
    __builtin_amdgcn_s_setprio(1);                                            \
    _Pragma("unroll") for (int m = 0; m < 8; ++m)                             \
        _Pragma("unroll") for (int n = 0; n < 4; ++n)                         \
            acc[m][n] = __builtin_amdgcn_mfma_f32_16x16x32_bf16(              \
                av[m], bv[n], acc[m][n], 0, 0, 0);                            \
    __builtin_amdgcn_s_setprio(0);                                            \
  }

  const int nt = K >> 5;  // 32 K-tiles
  STAGE(0, 0);
  STAGE(1, 1);
  STAGE(2, 2);

  for (int t = 0; t < nt - 3; ++t) {
    // Drain until only tiles t+1,t+2 (2 tiles x 4 loads = 8) remain in
    // flight -> tile t's loads (oldest, in-order retire) have landed.
    asm volatile("s_waitcnt vmcnt(8)" ::: "memory");
    __builtin_amdgcn_s_barrier();
    const char* base = smem + (t & 3) * 32768;
    bf16x8 av[8], bv[4];
#pragma unroll
    for (int m = 0; m < 8; ++m)
      av[m] = *(const bf16x8*)(base + aoff + m * 1024);
#pragma unroll
    for (int n = 0; n < 4; ++n)
      bv[n] = *(const bf16x8*)(base + boff + n * 1024);
    STAGE((t + 3) & 3, t + 3);   // into buffer freed at end of iter t-1
    __builtin_amdgcn_s_setprio(1);
#pragma unroll
    for (int m = 0; m < 8; ++m)
#pragma unroll
      for (int n = 0; n < 4; ++n)
        acc[m][n] = __builtin_amdgcn_mfma_f32_16x16x32_bf16(av[m], bv[n],
                                                            acc[m][n], 0, 0, 0);
    __builtin_amdgcn_s_setprio(0);
    // all my ds_reads of buf t&3 done -> buffer reusable after barrier
    asm volatile("s_waitcnt lgkmcnt(0)" ::: "memory");
    __builtin_amdgcn_s_barrier();
  }
  // tail: tiles nt-3, nt-2, nt-1 (no more staging)
  asm volatile("s_waitcnt vmcnt(8)" ::: "memory");
  __builtin_amdgcn_s_barrier();
  MFMAS(smem + ((nt - 3) & 3) * 32768);
  asm volatile("s_waitcnt vmcnt(4)" ::: "memory");
  __builtin_amdgcn_s_barrier();
  MFMAS(smem + ((nt - 2) & 3) * 32768);
  asm volatile("s_waitcnt vmcnt(0)" ::: "memory");
  __builtin_amdgcn_s_barrier();
  MFMAS(smem + ((nt - 1) & 3) * 32768);

  // ---- epilogue: C/D frag mapping col = lane&15, row = (lane>>4)*4 + i
  const int r4 = (lane >> 4) * 4;
#pragma unroll
  for (int n = 0; n < 4; ++n) {
    const int col = n0 + wc * 64 + n * 16 + fr;
    const float bvv = bias[col];
#pragma unroll
    for (int m = 0; m < 8; ++m) {
      const int row = m0 + wr * 128 + m * 16 + r4;
#pragma unroll
      for (int i = 0; i < 4; ++i) {
        const size_t idx = (size_t)(row + i) * N + col;
        float v = acc[m][n][i] + bvv;
        if constexpr (EPI == 0) {
          Ob[idx] = f2bf(v);
        } else {
          Of[idx] = v + resid[idx];
        }
      }
    }
  }
#undef STAGE
#undef MFMAS
}

// ---------------- head-wise attention, MFMA, one wave per row b ----------
// Q,K,V: [B, 16 heads, 64 dims] bf16.  Out: [B, 1024] with idx = d*16 + h.
// Scores computed TRANSPOSED: D' = mfma(K_frag, Q_frag) -> D'[g, h] with
// col h = lane&15, row g = (lane>>4)*4 + i.  Softmax over g = in-reg over i
// + shfl_xor(16,32).  The resulting P at lane L (regs j) is EXACTLY the
// A-fragment layout for mfma_f32_16x16x16_bf16 (A[h=L&15][g=(L>>4)*4+j]),
// so PV needs no transpose at all.
__global__ __launch_bounds__(256) void attn_kernel(
    const unsigned short* __restrict__ Q, const unsigned short* __restrict__ K,
    const unsigned short* __restrict__ V, unsigned short* __restrict__ O) {
  const int tid  = threadIdx.x;
  const int lane = tid & 63;
  const int wave = tid >> 6;
  const int b    = blockIdx.x * 4 + wave;
  const size_t base = (size_t)b * 1024;
  const int fr = lane & 15, kg = lane >> 4;

  // ---- QK^T (transposed): A = K rows (g), B = Q rows (h), K-dim = d (64).
  const bf16x8 kf0 = *(const bf16x8*)(K + base + fr * 64 + kg * 8);
  const bf16x8 kf1 = *(const bf16x8*)(K + base + fr * 64 + 32 + kg * 8);
  const bf16x8 qf0 = *(const bf16x8*)(Q + base + fr * 64 + kg * 8);
  const bf16x8 qf1 = *(const bf16x8*)(Q + base + fr * 64 + 32 + kg * 8);

  // ---- V B-fragments for the 4 d-chunks: lane (fr=d_local, kg) holds
  // V[kg*4+j][c*16+fr], j=0..3.
  s16x4 vb[4];
#pragma unroll
  for (int c = 0; c < 4; ++c) {
    const unsigned short* vp = V + base + c * 16 + fr + kg * 4 * 64;
    s16x4 t;
    t[0] = (short)vp[0];
    t[1] = (short)vp[64];
    t[2] = (short)vp[128];
    t[3] = (short)vp[192];
    vb[c] = t;
  }

  f32x4 es = (f32x4)0.0f;
  es = __builtin_amdgcn_mfma_f32_16x16x32_bf16(kf0, qf0, es, 0, 0, 0);
  es = __builtin_amdgcn_mfma_f32_16x16x32_bf16(kf1, qf1, es, 0, 0, 0);

  // ---- softmax over g (rows): reduce 4 in-lane values + lanes L^16, L^32.
  float s0 = es[0] * 0.125f, s1 = es[1] * 0.125f;
  float s2 = es[2] * 0.125f, s3 = es[3] * 0.125f;
  float mx = fmaxf(fmaxf(s0, s1), fmaxf(s2, s3));
  mx = fmaxf(mx, __shfl_xor(mx, 16, 64));
  mx = fmaxf(mx, __shfl_xor(mx, 32, 64));
  float e0 = __expf(s0 - mx), e1 = __expf(s1 - mx);
  float e2 = __expf(s2 - mx), e3 = __expf(s3 - mx);
  float sum = e0 + e1 + e2 + e3;
  sum += __shfl_xor(sum, 16, 64);
  sum += __shfl_xor(sum, 32, 64);
  const float inv = 1.0f / sum;

  s16x4 pa;
  pa[0] = (short)f2bf(e0 * inv);
  pa[1] = (short)f2bf(e1 * inv);
  pa[2] = (short)f2bf(e2 * inv);
  pa[3] = (short)f2bf(e3 * inv);

  // ---- PV: out[h, c*16+d'] via 4x mfma_f32_16x16x16_bf16 (K = g = 16).
  unsigned short* Ob = O + base;
#pragma unroll
  for (int c = 0; c < 4; ++c) {
    f32x4 o = __builtin_amdgcn_mfma_f32_16x16x16bf16_1k(pa, vb[c],
                                                        (f32x4)0.0f, 0, 0, 0);
    // D layout: col d' = fr, row h = kg*4 + i  ->  out idx = (c*16+fr)*16 + h
    uint2 st;
    st.x = (uint32)f2bf(o[0]) | ((uint32)f2bf(o[1]) << 16);
    st.y = (uint32)f2bf(o[2]) | ((uint32)f2bf(o[3]) << 16);
    *(uint2*)(Ob + c * 256 + fr * 16 + kg * 4) = st;
  }
}

// ---------------- in-place LayerNorm over rows of 1024 ----------------
__global__ __launch_bounds__(256) void ln_kernel(
    float* __restrict__ Y, const float* __restrict__ gw,
    const float* __restrict__ gb) {
  float* y = Y + (size_t)blockIdx.x * 1024;
  const int tid = threadIdx.x;
  float4 v = ((const float4*)y)[tid];
  float s  = v.x + v.y + v.z + v.w;
  float s2 = v.x * v.x + v.y * v.y + v.z * v.z + v.w * v.w;
#pragma unroll
  for (int o = 32; o > 0; o >>= 1) {
    s  += __shfl_xor(s, o, 64);
    s2 += __shfl_xor(s2, o, 64);
  }
  __shared__ float rs[4], rq[4];
  const int wave = tid >> 6;
  if ((tid & 63) == 0) { rs[wave] = s; rq[wave] = s2; }
  __syncthreads();
  s  = rs[0] + rs[1] + rs[2] + rs[3];
  s2 = rq[0] + rq[1] + rq[2] + rq[3];
  const float mean = s * (1.f / 1024.f);
  const float var  = s2 * (1.f / 1024.f) - mean * mean;
  const float r = rsqrtf(var + 1e-5f);
  const float4 w = ((const float4*)gw)[tid];
  const float4 bb = ((const float4*)gb)[tid];
  float4 o;
  o.x = (v.x - mean) * r * w.x + bb.x;
  o.y = (v.y - mean) * r * w.y + bb.y;
  o.z = (v.z - mean) * r * w.z + bb.z;
  o.w = (v.w - mean) * r * w.w + bb.w;
  ((float4*)y)[tid] = o;
}

extern "C" void kernel_launch(void* const* d_in, const int* in_sizes, int n_in,
                              void* d_out, int out_size, void* d_ws,
                              size_t ws_size, hipStream_t stream) {
  const float* sa = (const float*)d_in[0];
  const float* st = (const float*)d_in[1];
  const float* Wq = (const float*)d_in[2];
  const float* bq = (const float*)d_in[3];
  const float* Wk = (const float*)d_in[4];
  const float* bk = (const float*)d_in[5];
  const float* Wv = (const float*)d_in[6];
  const float* bv = (const float*)d_in[7];
  const float* Wo = (const float*)d_in[8];
  const float* bo = (const float*)d_in[9];
  const float* lw = (const float*)d_in[10];
  const float* lb = (const float*)d_in[11];
  float* out = (float*)d_out;

  const int M = 32768, D = 1024;
  const size_t MiB = 1024 * 1024;
  char* w = (char*)d_ws;
  unsigned short* saB = (unsigned short*)(w);                // 64 MiB
  unsigned short* stB = (unsigned short*)(w + 64 * MiB);     // 64 MiB
  unsigned short* WqB = (unsigned short*)(w + 128 * MiB);    // 2 MiB
  unsigned short* WkB = (unsigned short*)(w + 130 * MiB);
  unsigned short* WvB = (unsigned short*)(w + 132 * MiB);
  unsigned short* WoB = (unsigned short*)(w + 134 * MiB);
  unsigned short* Vb  = (unsigned short*)(w + 136 * MiB);    // 64 MiB -> ws = 200 MiB
  // Q and K live in d_out (128 MiB fp32) -- both dead before O-proj writes it.
  unsigned short* Qb = (unsigned short*)d_out;
  unsigned short* Kb = (unsigned short*)d_out + (size_t)M * D;
  unsigned short* attb = saB;  // sa_bf16 is dead after the Q GEMM

  const int nH8 = M * D / 8;
  const int nW8 = D * D / 8;
  cast_kernel<<<nH8 / 256, 256, 0, stream>>>(sa, saB, nH8);
  cast_kernel<<<nH8 / 256, 256, 0, stream>>>(st, stB, nH8);
  cast_kernel<<<nW8 / 256, 256, 0, stream>>>(Wq, WqB, nW8);
  cast_kernel<<<nW8 / 256, 256, 0, stream>>>(Wk, WkB, nW8);
  cast_kernel<<<nW8 / 256, 256, 0, stream>>>(Wv, WvB, nW8);
  cast_kernel<<<nW8 / 256, 256, 0, stream>>>(Wo, WoB, nW8);

  const int nblk = (M / 256) * (D / 256);   // 512
  gemm256<0><<<nblk, 512, 0, stream>>>(saB, WqB, bq, nullptr, Qb, nullptr, M, D, D);
  gemm256<0><<<nblk, 512, 0, stream>>>(stB, WkB, bk, nullptr, Kb, nullptr, M, D, D);
  gemm256<0><<<nblk, 512, 0, stream>>>(stB, WvB, bv, nullptr, Vb, nullptr, M, D, D);

  attn_kernel<<<M / 4, 256, 0, stream>>>(Qb, Kb, Vb, attb);

  gemm256<1><<<nblk, 512, 0, stream>>>(attb, WoB, bo, sa, nullptr, out, M, D, D);

  ln_kernel<<<M, 256, 0, stream>>>(out, lw, lb);
}